// Round 1
// baseline (1666.291 us; speedup 1.0000x reference)
//
#include <hip/hip_runtime.h>

#define HW 2304          // 48*48
#define NB 8             // batch
#define NC 256           // input channels
#define HID 128          // heads*dim_head
#define DH 32            // dim_head
#define NH 4             // heads
#define SCALE 0.17677669529663687f  // 1/sqrt(32)

// ---------------------------------------------------------------------------
// K1/K3: tiled fp32 GEMM for 1x1 conv.  out[o][s] = sum_c W[o][c]*B[c][s]+bias
// Tile: M64 x N128, K-tile 16, 256 threads, 4x8 micro-tile per thread.
// QKV=true: M=384, store Q natural [b][c][s], K/V transposed [bh][j][d].
// QKV=false: M=256, store natural to d_out. Both accumulate -0.5*sum(v^2).
// ---------------------------------------------------------------------------
template<int KDIM, bool QKV>
__global__ __launch_bounds__(256)
void conv1x1(const float* __restrict__ Bin, const float* __restrict__ Wt,
             const float* __restrict__ bias,
             float* __restrict__ out0, float* __restrict__ Ktb,
             float* __restrict__ Vtb, float* __restrict__ E)
{
    const int b  = blockIdx.z;
    const int bm = blockIdx.y * 64;
    const int bn = blockIdx.x * 128;
    const int t  = threadIdx.x;
    const int tx = t & 15;      // n group (8 cols)
    const int ty = t >> 4;      // m group (4 rows)

    __shared__ float As[16][68];    // [c][m], pad to 68 (16B-aligned rows)
    __shared__ float Bs[16][132];   // [c][n], pad to 132
    __shared__ float red[4];

    const float* Bb = Bin + (size_t)b * KDIM * HW;

    float acc[4][8];
    #pragma unroll
    for (int i = 0; i < 4; ++i)
        #pragma unroll
        for (int j = 0; j < 8; ++j) acc[i][j] = 0.f;

    for (int k0 = 0; k0 < KDIM; k0 += 16) {
        {   // load A tile 64x16
            const int c = t & 15, m0 = t >> 4;
            #pragma unroll
            for (int it = 0; it < 4; ++it) {
                const int m = m0 + it * 16;
                As[c][m] = Wt[(size_t)(bm + m) * KDIM + k0 + c];
            }
        }
        {   // load B tile 16x128
            const int n = t & 127, c0 = t >> 7;
            #pragma unroll
            for (int it = 0; it < 8; ++it) {
                const int c = c0 + it * 2;
                Bs[c][n] = Bb[(size_t)(k0 + c) * HW + bn + n];
            }
        }
        __syncthreads();
        #pragma unroll
        for (int c = 0; c < 16; ++c) {
            float a[4], bb[8];
            #pragma unroll
            for (int i = 0; i < 4; ++i) a[i] = As[c][ty * 4 + i];
            #pragma unroll
            for (int j = 0; j < 8; ++j) bb[j] = Bs[c][tx * 8 + j];
            #pragma unroll
            for (int i = 0; i < 4; ++i)
                #pragma unroll
                for (int j = 0; j < 8; ++j) acc[i][j] += a[i] * bb[j];
        }
        __syncthreads();
    }

    float e = 0.f;
    #pragma unroll
    for (int i = 0; i < 4; ++i) {
        const int o = bm + ty * 4 + i;
        const float bv = bias[o];
        #pragma unroll
        for (int j = 0; j < 8; ++j) {
            const int s = bn + tx * 8 + j;
            const float v = acc[i][j] + bv;
            e -= 0.5f * v * v;
            if (QKV) {
                if (o < HID) {
                    out0[((size_t)b * HID + o) * HW + s] = v;           // Q natural
                } else if (o < 2 * HID) {
                    const int c = o - HID;
                    Ktb[((size_t)(b * NH + (c >> 5)) * HW + s) * DH + (c & 31)] = v;
                } else {
                    const int c = o - 2 * HID;
                    Vtb[((size_t)(b * NH + (c >> 5)) * HW + s) * DH + (c & 31)] = v;
                }
            } else {
                out0[((size_t)b * NC + o) * HW + s] = v;
            }
        }
    }
    // block energy reduction -> one atomic
    #pragma unroll
    for (int off = 32; off > 0; off >>= 1) e += __shfl_down(e, off);
    if ((t & 63) == 0) red[t >> 6] = e;
    __syncthreads();
    if (t == 0) atomicAdd(E, red[0] + red[1] + red[2] + red[3]);
}

// ---------------------------------------------------------------------------
// K2: flash attention. Block = 256 thr = 4 waves; 64 queries/block; each wave
// handles a quarter of the 2304 keys (key-split for occupancy), then LDS merge.
// Per thread: one query row; online softmax with running m, l, t=sum p*(s-m).
// e_attn row = t/l - log(l).  att output [b][h*32+d][i] = O[d]/l.
// ---------------------------------------------------------------------------
__global__ __launch_bounds__(256)
void flash_attn(const float* __restrict__ Q, const float* __restrict__ Ktb,
                const float* __restrict__ Vtb, float* __restrict__ att,
                float* __restrict__ E)
{
    const int bh   = blockIdx.y;              // b*4+h
    const int lane = threadIdx.x & 63;
    const int wid  = threadIdx.x >> 6;        // key-split index 0..3
    const int i    = blockIdx.x * 64 + lane;  // query row

    const float* Qp = Q + (size_t)bh * DH * HW + i;
    float q[DH];
    #pragma unroll
    for (int d = 0; d < DH; ++d) q[d] = Qp[(size_t)d * HW] * SCALE;

    const float* Kp = Ktb + (size_t)bh * HW * DH;
    const float* Vp = Vtb + (size_t)bh * HW * DH;

    float m = -1e30f, l = 0.f, tE = 0.f;
    float o[DH];
    #pragma unroll
    for (int d = 0; d < DH; ++d) o[d] = 0.f;

    const int j0 = wid * (HW / 4), j1 = j0 + (HW / 4);
    for (int j = j0; j < j1; ++j) {
        const float4* kj = (const float4*)(Kp + (size_t)j * DH);
        float s = 0.f;
        #pragma unroll
        for (int d4 = 0; d4 < DH / 4; ++d4) {
            const float4 kv = kj[d4];
            s += q[d4*4+0]*kv.x + q[d4*4+1]*kv.y + q[d4*4+2]*kv.z + q[d4*4+3]*kv.w;
        }
        // load V early so latency overlaps the softmax update
        float4 vv[DH / 4];
        const float4* vj = (const float4*)(Vp + (size_t)j * DH);
        #pragma unroll
        for (int d4 = 0; d4 < DH / 4; ++d4) vv[d4] = vj[d4];

        if (s > m) {                    // new running max: rescale
            const float al = __expf(m - s);
            tE = al * (tE + (m - s) * l);
            l *= al;
            #pragma unroll
            for (int d = 0; d < DH; ++d) o[d] *= al;
            m = s;
        }
        const float p = __expf(s - m);
        l  += p;
        tE += p * (s - m);
        #pragma unroll
        for (int d4 = 0; d4 < DH / 4; ++d4) {
            o[d4*4+0] += p * vv[d4].x; o[d4*4+1] += p * vv[d4].y;
            o[d4*4+2] += p * vv[d4].z; o[d4*4+3] += p * vv[d4].w;
        }
    }

    // publish partials (pad inner dim to 33 to kill bank conflicts)
    __shared__ float sm[4][64], sl[4][64], st[4][64];
    __shared__ float so[4][64][DH + 1];
    sm[wid][lane] = m; sl[wid][lane] = l; st[wid][lane] = tE;
    #pragma unroll
    for (int d = 0; d < DH; ++d) so[wid][lane][d] = o[d];
    __syncthreads();

    if (wid == 0) {   // wave 0 merges the 4 key-split partials per query
        float mM = sm[0][lane];
        #pragma unroll
        for (int w = 1; w < 4; ++w) mM = fmaxf(mM, sm[w][lane]);
        float L = 0.f, T = 0.f, O[DH];
        #pragma unroll
        for (int d = 0; d < DH; ++d) O[d] = 0.f;
        #pragma unroll
        for (int w = 0; w < 4; ++w) {
            const float mw = sm[w][lane];
            const float al = __expf(mw - mM);
            L += sl[w][lane] * al;
            T += (st[w][lane] + (mw - mM) * sl[w][lane]) * al;
            #pragma unroll
            for (int d = 0; d < DH; ++d) O[d] += so[w][lane][d] * al;
        }
        float e = T / L - __logf(L);
        const float invl = 1.f / L;
        float* ap = att + (size_t)bh * DH * HW + i;
        #pragma unroll
        for (int d = 0; d < DH; ++d) ap[(size_t)d * HW] = O[d] * invl;
        #pragma unroll
        for (int off = 32; off > 0; off >>= 1) e += __shfl_down(e, off);
        if (lane == 0) atomicAdd(E, e);
    }
}

__global__ void write_energy(const float* __restrict__ E, float* __restrict__ dst)
{
    if (threadIdx.x == 0) dst[0] = E[0];
}

// ---------------------------------------------------------------------------
extern "C" void kernel_launch(void* const* d_in, const int* in_sizes, int n_in,
                              void* d_out, int out_size, void* d_ws, size_t ws_size,
                              hipStream_t stream) {
    const float* x     = (const float*)d_in[0];
    const float* w_qkv = (const float*)d_in[1];
    const float* b_qkv = (const float*)d_in[2];
    const float* w_out = (const float*)d_in[3];
    const float* b_out = (const float*)d_in[4];
    float* out = (float*)d_out;

    float* wsf = (float*)d_ws;
    float* E   = wsf;                               // [0]: energy accumulator
    float* Q   = wsf + 16;                          // [b][128][2304]
    float* Kt  = Q  + (size_t)NB * HID * HW;        // [bh][2304][32]
    float* Vt  = Kt + (size_t)NB * NH * HW * DH;    // [bh][2304][32]
    float* att = Vt + (size_t)NB * NH * HW * DH;    // [b][128][2304]

    hipMemsetAsync(d_ws, 0, 64, stream);            // zero energy accumulator

    conv1x1<NC, true ><<<dim3(18, 6, NB), 256, 0, stream>>>(x, w_qkv, b_qkv,
                                                            Q, Kt, Vt, E);
    flash_attn<<<dim3(HW / 64, NB * NH), 256, 0, stream>>>(Q, Kt, Vt, att, E);
    conv1x1<HID, false><<<dim3(18, 4, NB), 256, 0, stream>>>(att, w_out, b_out,
                                                             out, nullptr, nullptr, E);
    write_energy<<<1, 1, 0, stream>>>(E, out + (size_t)NB * NC * HW);
}

// Round 4
// 326.233 us; speedup vs baseline: 5.1077x; 5.1077x over previous
//
#include <hip/hip_runtime.h>

#define HW 2304          // 48*48
#define NB 8             // batch
#define NC 256           // input channels
#define HID 128          // heads*dim_head
#define DH 32            // dim_head
#define NH 4             // heads
#define SCALE 0.17677669529663687f  // 1/sqrt(32)

using bf16x8 = __attribute__((ext_vector_type(8))) short;
using f32x4  = __attribute__((ext_vector_type(4))) float;

__device__ __forceinline__ short f2bf(float f) {   // RNE float->bf16
    unsigned u = __float_as_uint(f);
    u += 0x7FFF + ((u >> 16) & 1);
    return (short)(u >> 16);
}

// ---------------------------------------------------------------------------
// K1/K3: tiled fp32 GEMM for 1x1 conv.  out[o][s] = sum_c W[o][c]*B[c][s]+bias
// QKV=true (M=384): emit bf16 Q*SCALE and K as [bh][s][dh], V as [bh][dh][s].
// QKV=false (M=256): fp32 natural to d_out. Both accumulate -0.5*sum(v^2).
// ---------------------------------------------------------------------------
template<int KDIM, bool QKV>
__global__ __launch_bounds__(256)
void conv1x1(const float* __restrict__ Bin, const float* __restrict__ Wt,
             const float* __restrict__ bias, float* __restrict__ out0,
             short* __restrict__ Qb, short* __restrict__ Kb,
             short* __restrict__ Vb, float* __restrict__ E)
{
    const int b  = blockIdx.z;
    const int bm = blockIdx.y * 64;
    const int bn = blockIdx.x * 128;
    const int t  = threadIdx.x;
    const int tx = t & 15;      // n group (8 cols)
    const int ty = t >> 4;      // m group (4 rows)

    __shared__ float As[16][68];
    __shared__ float Bs[16][132];
    __shared__ float red[4];

    const float* Bb = Bin + (size_t)b * KDIM * HW;

    float acc[4][8];
    #pragma unroll
    for (int i = 0; i < 4; ++i)
        #pragma unroll
        for (int j = 0; j < 8; ++j) acc[i][j] = 0.f;

    for (int k0 = 0; k0 < KDIM; k0 += 16) {
        {   // A tile 64x16
            const int c = t & 15, m0 = t >> 4;
            #pragma unroll
            for (int it = 0; it < 4; ++it) {
                const int m = m0 + it * 16;
                As[c][m] = Wt[(size_t)(bm + m) * KDIM + k0 + c];
            }
        }
        {   // B tile 16x128
            const int n = t & 127, c0 = t >> 7;
            #pragma unroll
            for (int it = 0; it < 8; ++it) {
                const int c = c0 + it * 2;
                Bs[c][n] = Bb[(size_t)(k0 + c) * HW + bn + n];
            }
        }
        __syncthreads();
        #pragma unroll
        for (int c = 0; c < 16; ++c) {
            float a[4], bb[8];
            #pragma unroll
            for (int i = 0; i < 4; ++i) a[i] = As[c][ty * 4 + i];
            #pragma unroll
            for (int j = 0; j < 8; ++j) bb[j] = Bs[c][tx * 8 + j];
            #pragma unroll
            for (int i = 0; i < 4; ++i)
                #pragma unroll
                for (int j = 0; j < 8; ++j) acc[i][j] += a[i] * bb[j];
        }
        __syncthreads();
    }

    float e = 0.f;
    #pragma unroll
    for (int i = 0; i < 4; ++i) {
        const int o = bm + ty * 4 + i;
        const float bv = bias[o];
        #pragma unroll
        for (int j = 0; j < 8; ++j) {
            const int s = bn + tx * 8 + j;
            const float v = acc[i][j] + bv;
            e -= 0.5f * v * v;
            if (QKV) {
                if (o < HID) {
                    const int h = o >> 5, dh = o & 31;
                    Qb[((size_t)(b * NH + h) * HW + s) * DH + dh] = f2bf(v * SCALE);
                } else if (o < 2 * HID) {
                    const int c = o - HID, h = c >> 5, dh = c & 31;
                    Kb[((size_t)(b * NH + h) * HW + s) * DH + dh] = f2bf(v);
                } else {
                    const int c = o - 2 * HID, h = c >> 5, dh = c & 31;
                    Vb[((size_t)(b * NH + h) * DH + dh) * HW + s] = f2bf(v);
                }
            } else {
                out0[((size_t)b * NC + o) * HW + s] = v;
            }
        }
    }
    #pragma unroll
    for (int off = 32; off > 0; off >>= 1) e += __shfl_down(e, off);
    if ((t & 63) == 0) red[t >> 6] = e;
    __syncthreads();
    if (t == 0) atomicAdd(E, red[0] + red[1] + red[2] + red[3]);
}

// ---------------------------------------------------------------------------
// K2: MFMA flash attention. Block = 4 waves; each wave owns 16 queries and
// iterates all 2304 keys in chunks of 32. Fixed softmax shift m=0 (|s|<~1,
// shift-invariant energy). S = Q.K^T via 2 mfma_16x16x32_bf16; P (C-layout)
// -> LDS (bf16, padded) -> A-layout frags; PV via 2 mfma. Deferred l/T row
// reductions after the key loop.  e_attn row = T/L - log(L).
// ---------------------------------------------------------------------------
__global__ __launch_bounds__(256)
void flash_attn_mfma(const short* __restrict__ Qb, const short* __restrict__ Kb,
                     const short* __restrict__ Vb, float* __restrict__ att,
                     float* __restrict__ E)
{
    const int bh   = blockIdx.y;
    const int wid  = threadIdx.x >> 6;
    const int lane = threadIdx.x & 63;
    const int n16  = lane & 15;
    const int quad = lane >> 4;
    const int qb   = blockIdx.x * 64 + wid * 16;

    __shared__ short Pl[4][16][40];     // per-wave P tile, stride 40 (2-way bank alias = free)
    short (*Pw)[40] = Pl[wid];

    // Q A-frag: A[m=lane&15][k=quad*8+j]
    const bf16x8 aq = *(const bf16x8*)(Qb + ((size_t)bh * HW + qb + n16) * DH + quad * 8);

    const short* kp = Kb + (size_t)bh * HW * DH;   // [key][dh]
    const short* vp = Vb + (size_t)bh * DH * HW;   // [dh][key]

    f32x4 acc0 = {0.f, 0.f, 0.f, 0.f}, acc1 = {0.f, 0.f, 0.f, 0.f};
    float lsum[4] = {0.f, 0.f, 0.f, 0.f}, tsum[4] = {0.f, 0.f, 0.f, 0.f};

    for (int c0 = 0; c0 < HW; c0 += 32) {
        // K^T B-frags: B[k=dh=quad*8+j][n=key=lane&15]
        const bf16x8 bk0 = *(const bf16x8*)(kp + (size_t)(c0 + n16) * DH + quad * 8);
        const bf16x8 bk1 = *(const bf16x8*)(kp + (size_t)(c0 + 16 + n16) * DH + quad * 8);
        // V B-frags: B[k=key=quad*8+j][n=dh=lane&15]
        const bf16x8 bv0 = *(const bf16x8*)(vp + (size_t)n16 * HW + c0 + quad * 8);
        const bf16x8 bv1 = *(const bf16x8*)(vp + (size_t)(n16 + 16) * HW + c0 + quad * 8);

        f32x4 z = {0.f, 0.f, 0.f, 0.f};
        f32x4 s0 = __builtin_amdgcn_mfma_f32_16x16x32_bf16(aq, bk0, z, 0, 0, 0);
        f32x4 s1 = __builtin_amdgcn_mfma_f32_16x16x32_bf16(aq, bk1, z, 0, 0, 0);

        // softmax with m=0; C-layout: row=quad*4+r (query), col=lane&15 (key)
        #pragma unroll
        for (int r = 0; r < 4; ++r) {
            const float p0 = __expf(s0[r]);
            const float p1 = __expf(s1[r]);
            lsum[r] += p0 + p1;
            tsum[r] += p0 * s0[r] + p1 * s1[r];
            Pw[quad * 4 + r][n16]      = f2bf(p0);
            Pw[quad * 4 + r][16 + n16] = f2bf(p1);
        }
        // wave-internal LDS round-trip: C-layout -> A-layout
        const bf16x8 pa = *(const bf16x8*)(&Pw[n16][quad * 8]);
        acc0 = __builtin_amdgcn_mfma_f32_16x16x32_bf16(pa, bv0, acc0, 0, 0, 0);
        acc1 = __builtin_amdgcn_mfma_f32_16x16x32_bf16(pa, bv1, acc1, 0, 0, 0);
    }

    // reduce l,T across the 16 lanes of each quad-group
    #pragma unroll
    for (int m = 1; m < 16; m <<= 1) {
        #pragma unroll
        for (int r = 0; r < 4; ++r) {
            lsum[r] += __shfl_xor(lsum[r], m);
            tsum[r] += __shfl_xor(tsum[r], m);
        }
    }

    float e = 0.f;
    #pragma unroll
    for (int r = 0; r < 4; ++r) {
        const int q = qb + quad * 4 + r;
        const float invl = 1.f / lsum[r];
        att[((size_t)bh * DH + n16) * HW + q]      = acc0[r] * invl;
        att[((size_t)bh * DH + 16 + n16) * HW + q] = acc1[r] * invl;
        e += tsum[r] * invl - __logf(lsum[r]);
    }
    e = (n16 == 0) ? e : 0.f;           // one lane per quad-group contributes
    e += __shfl_xor(e, 16);
    e += __shfl_xor(e, 32);
    if (lane == 0) atomicAdd(E, e);
}

__global__ void write_energy(const float* __restrict__ E, float* __restrict__ dst)
{
    if (threadIdx.x == 0) dst[0] = E[0];
}

// ---------------------------------------------------------------------------
extern "C" void kernel_launch(void* const* d_in, const int* in_sizes, int n_in,
                              void* d_out, int out_size, void* d_ws, size_t ws_size,
                              hipStream_t stream) {
    const float* x     = (const float*)d_in[0];
    const float* w_qkv = (const float*)d_in[1];
    const float* b_qkv = (const float*)d_in[2];
    const float* w_out = (const float*)d_in[3];
    const float* b_out = (const float*)d_in[4];
    float* out = (float*)d_out;

    float* wsf = (float*)d_ws;
    float* E   = wsf;                                  // energy accumulator
    float* att = wsf + 16;                             // fp32 [b][128][2304]
    short* Qb  = (short*)(att + (size_t)NB * HID * HW);
    short* Kb  = Qb + (size_t)NB * NH * HW * DH;       // bf16 [bh][s][dh]
    short* Vb  = Kb + (size_t)NB * NH * HW * DH;       // bf16 [bh][dh][s]

    (void)hipMemsetAsync(d_ws, 0, 64, stream);         // zero energy accumulator

    conv1x1<NC, true ><<<dim3(18, 6, NB), 256, 0, stream>>>(
        x, w_qkv, b_qkv, nullptr, Qb, Kb, Vb, E);
    flash_attn_mfma<<<dim3(HW / 64, NB * NH), 256, 0, stream>>>(
        Qb, Kb, Vb, att, E);
    conv1x1<HID, false><<<dim3(18, 4, NB), 256, 0, stream>>>(
        att, w_out, b_out, out, nullptr, nullptr, nullptr, E);
    write_energy<<<1, 1, 0, stream>>>(E, out + (size_t)NB * NC * HW);
}